// Round 5
// baseline (221.110 us; speedup 1.0000x reference)
//
#include <hip/hip_runtime.h>

#define NV 50000
#define F 128
#define K 20
#define KCAT 256   // concatenated inner dim: [V | vagg]

typedef __attribute__((ext_vector_type(8))) __bf16 bf16x8;
typedef __attribute__((ext_vector_type(4))) float f32x4;

__device__ inline ushort f2bf(float x) {     // RNE f32 -> bf16
    uint u = __float_as_uint(x);
    return (ushort)((u + 0x7fffu + ((u >> 16) & 1u)) >> 16);
}

// ws layout (bf16): vb=[NV][256] (cols 0..127 = bf16(V), 128..255 = bf16(vagg))
//                   wt=[128][256] wt[c][k] = bf16(Wcat[k][c])

// ---------------------------------------------------------------------------
// prep: blocks 0..6249 convert V fp32->bf16 (f32x4/thread); remaining 128
// blocks build the transposed bf16 weight matrix.
// ---------------------------------------------------------------------------
__global__ __launch_bounds__(256) void prep_kernel(
    const f32x4* __restrict__ v4, ushort* __restrict__ vb,
    const float* __restrict__ Wvc, const float* __restrict__ Wvn,
    ushort* __restrict__ wt)
{
    int bid = blockIdx.x;
    if (bid < NV * F / 4 / 256) {          // 6250 blocks
        int t = bid * 256 + threadIdx.x;
        int e = t * 4;
        int row = e >> 7, f = e & 127;
        f32x4 x = __builtin_nontemporal_load(v4 + t);   // read-once stream
        uint2 o;
        o.x = (uint)f2bf(x[0]) | ((uint)f2bf(x[1]) << 16);
        o.y = (uint)f2bf(x[2]) | ((uint)f2bf(x[3]) << 16);
        *reinterpret_cast<uint2*>(vb + (size_t)row * KCAT + f) = o;
    } else {
        int t = (bid - NV * F / 4 / 256) * 256 + threadIdx.x;  // < 32768
        int c = t >> 8, k = t & 255;
        float w = (k < F) ? Wvc[k * F + c] : Wvn[(k - F) * F + c];
        wt[t] = f2bf(w);
    }
}

// ---------------------------------------------------------------------------
// agg (feature-sliced): slice = bid & 3 -> 32 features = 16 uints = 64B/row.
// bid%8 -> XCD round-robin => XCD x only gathers slice x&3 (3.2 MB, fits the
// private 4 MB L2). idx/edge streams use NON-TEMPORAL loads so they don't
// evict the gather slice from L2. 16 rows/block (4/wave, 16 lanes/row).
// Reads vb uints [16s,16s+16); writes uints [64+16s,64+16s+16) -> no race.
// ---------------------------------------------------------------------------
__global__ __launch_bounds__(256) void agg_sliced(
    const uint* __restrict__ vb_u,   // [NV][128] uint view
    const int* __restrict__ nh_idx, const int* __restrict__ int_idx,
    const float* __restrict__ nh_e, const float* __restrict__ int_e,
    uint* __restrict__ vagg_u)       // same buffer
{
    const int bid   = blockIdx.x;
    const int slice = bid & 3;
    const int rb    = bid >> 2;
    const int lane  = threadIdx.x & 63;
    const int wave  = threadIdx.x >> 6;
    const int row   = rb * 16 + wave * 4 + (lane >> 4);
    const int q     = lane & 15;
    const uint* __restrict__ src = vb_u + slice * 16 + q;

    float ax = 0.f, ay = 0.f, cnt = (float)K;
    const long base = (long)row * K;

    #pragma unroll
    for (int k = 0; k < K; ++k) {
        int   j = __builtin_nontemporal_load(nh_idx + base + k);
        float w = __builtin_nontemporal_load(nh_e  + base + k);
        uint  p = src[(size_t)j * 128];
        ax = fmaf(w, __uint_as_float(p << 16), ax);
        ay = fmaf(w, __uint_as_float(p & 0xffff0000u), ay);
    }
    #pragma unroll
    for (int k = 0; k < K; ++k) {
        int   j = __builtin_nontemporal_load(int_idx + base + k);
        float w = __builtin_nontemporal_load(int_e  + base + k);
        bool  valid = (j >= 0);
        if (!valid) { j = 0; w = 0.f; }   // predicated; row 0 stays hot
        uint  p = src[(size_t)j * 128];
        ax = fmaf(w, __uint_as_float(p << 16), ax);
        ay = fmaf(w, __uint_as_float(p & 0xffff0000u), ay);
        cnt += valid ? 1.f : 0.f;
    }
    float inv = 1.f / cnt;
    vagg_u[(size_t)row * 128 + 64 + slice * 16 + q] =
        (uint)f2bf(ax * inv) | ((uint)f2bf(ay * inv) << 16);
}

// ---------------------------------------------------------------------------
// Fused MFMA GEMM: out = relu(vb[N,256] @ Wcat[256,128] + bv)
// ct loop is NOT unrolled (unroll 1) and the epilogue is inside it:
// only 8 B-loads + 1 acc live at a time -> no VGPR spill (the round-2/3
// version fully unrolled 64 B-loads = 256 VGPRs in flight).
// ---------------------------------------------------------------------------
__global__ __launch_bounds__(256) void gemm_fused(
    const ushort* __restrict__ vb,   // [NV][256] bf16
    const ushort* __restrict__ wt,   // [128][256] bf16
    const float* __restrict__ bv,
    float* __restrict__ out)
{
    const int lane = threadIdx.x & 63;
    const int wave = threadIdx.x >> 6;
    const int r0   = blockIdx.x * 64 + wave * 16;

    int arow = r0 + (lane & 15);
    if (arow >= NV) arow = NV - 1;           // clamp loads; stores guarded

    const bf16x8* abase = reinterpret_cast<const bf16x8*>(
        vb + (size_t)arow * KCAT + (lane >> 4) * 8);
    bf16x8 a[8];
    #pragma unroll
    for (int ks = 0; ks < 8; ++ks)
        a[ks] = __builtin_nontemporal_load(abase + ks * 4);  // read-once rows

    const ushort* wbase = wt + (size_t)(lane & 15) * KCAT + (lane >> 4) * 8;
    const int col0  = lane & 15;
    const int rbase = r0 + (lane >> 4) * 4;

    #pragma unroll 1
    for (int ct = 0; ct < 8; ++ct) {
        const bf16x8* wb = reinterpret_cast<const bf16x8*>(
            wbase + (size_t)ct * 16 * KCAT);
        f32x4 acc = (f32x4){0.f, 0.f, 0.f, 0.f};
        #pragma unroll
        for (int ks = 0; ks < 8; ++ks) {
            bf16x8 b = wb[ks * 4];           // cached: wt is hot in L1/L2
            acc = __builtin_amdgcn_mfma_f32_16x16x32_bf16(a[ks], b, acc, 0, 0, 0);
        }
        int c = ct * 16 + col0;
        float bb = bv[c];
        #pragma unroll
        for (int reg = 0; reg < 4; ++reg) {
            int r = rbase + reg;
            if (r < NV) {
                float z = acc[reg] + bb;
                __builtin_nontemporal_store(fmaxf(z, 0.f), out + (size_t)r * F + c);
            }
        }
    }
}

// ---------------------------------------------------------------------------
extern "C" void kernel_launch(void* const* d_in, const int* in_sizes, int n_in,
                              void* d_out, int out_size, void* d_ws, size_t ws_size,
                              hipStream_t stream)
{
    const float* v       = (const float*)d_in[0];
    const int*   nh_idx  = (const int*)  d_in[1];
    const int*   int_idx = (const int*)  d_in[2];
    const float* nh_e    = (const float*)d_in[3];
    const float* int_e   = (const float*)d_in[4];
    const float* Wvc     = (const float*)d_in[5];
    const float* Wvn     = (const float*)d_in[6];
    const float* bv      = (const float*)d_in[7];
    float* out = (float*)d_out;

    ushort* vb = (ushort*)d_ws;                       // NV*256 bf16 = 25.6 MB
    ushort* wt = vb + (size_t)NV * KCAT;              // 128*256 bf16 = 64 KB

    prep_kernel<<<NV * F / 4 / 256 + F * KCAT / 256, 256, 0, stream>>>(
        (const f32x4*)v, vb, Wvc, Wvn, wt);
    agg_sliced<<<(NV / 16) * 4, 256, 0, stream>>>((const uint*)vb, nh_idx, int_idx,
                                                  nh_e, int_e, (uint*)vb);
    gemm_fused<<<(NV + 63) / 64, 256, 0, stream>>>(vb, wt, bv, out);
}

// Round 7
// 179.364 us; speedup vs baseline: 1.2327x; 1.2327x over previous
//
#include <hip/hip_runtime.h>

#define NV 50000
#define F 128
#define K 20
#define KCAT 256   // concatenated inner dim: [V | vagg]
#define RPB 16     // rows per block in agg

typedef __attribute__((ext_vector_type(8))) __bf16 bf16x8;
typedef __attribute__((ext_vector_type(4))) float f32x4;

__device__ inline ushort f2bf(float x) {     // RNE f32 -> bf16
    uint u = __float_as_uint(x);
    return (ushort)((u + 0x7fffu + ((u >> 16) & 1u)) >> 16);
}

// ws layout (bf16): vb=[NV][256] (cols 0..127 = bf16(V), 128..255 = bf16(vagg))
//                   wt=[128][256] wt[c][k] = bf16(Wcat[k][c])

// ---------------------------------------------------------------------------
// prep: blocks 0..6249 convert V fp32->bf16 (f32x4/thread); remaining 128
// blocks build the transposed bf16 weight matrix.
// ---------------------------------------------------------------------------
__global__ __launch_bounds__(256) void prep_kernel(
    const f32x4* __restrict__ v4, ushort* __restrict__ vb,
    const float* __restrict__ Wvc, const float* __restrict__ Wvn,
    ushort* __restrict__ wt)
{
    int bid = blockIdx.x;
    if (bid < NV * F / 4 / 256) {          // 6250 blocks
        int t = bid * 256 + threadIdx.x;
        int e = t * 4;
        int row = e >> 7, f = e & 127;
        f32x4 x = __builtin_nontemporal_load(v4 + t);   // pure stream, deep TLP
        uint2 o;
        o.x = (uint)f2bf(x[0]) | ((uint)f2bf(x[1]) << 16);
        o.y = (uint)f2bf(x[2]) | ((uint)f2bf(x[3]) << 16);
        *reinterpret_cast<uint2*>(vb + (size_t)row * KCAT + f) = o;
    } else {
        int t = (bid - NV * F / 4 / 256) * 256 + threadIdx.x;  // < 32768
        int c = t >> 8, k = t & 255;
        float w = (k < F) ? Wvc[k * F + c] : Wvn[(k - F) * F + c];
        wt[t] = f2bf(w);
    }
}

// ---------------------------------------------------------------------------
// agg: block = 16 rows. Stage idx+edge (+validity) ONCE into LDS as int2{j,w}
// (5 KB), count denom via LDS atomics. Then wave w processes feature-slice w
// (32 feats = 16 uints = 64 B/row) for all 16 rows: 4 rows in flight
// (lane>>4), 16 lanes * 4 B per row-gather. Gathers for slice s confined to a
// 3.2 MB region; with bid%8->XCD round-robin each XCD's L2 holds its slice.
// idx/edge streams now read 1x (was 4x) and no nt hints anywhere.
// ---------------------------------------------------------------------------
__global__ __launch_bounds__(256) void agg_lds(
    const uint* __restrict__ vb_u,   // [NV][128] uint view
    const int* __restrict__ nh_idx, const int* __restrict__ int_idx,
    const float* __restrict__ nh_e, const float* __restrict__ int_e,
    uint* __restrict__ vagg_u)       // same buffer
{
    __shared__ int2 sJW[RPB][2 * K];   // {index, weight-bits}, invalid -> {0,0}
    __shared__ int  sCnt[RPB];

    const int tid = threadIdx.x;
    const int r0  = blockIdx.x * RPB;

    if (tid < RPB) sCnt[tid] = K;      // nh indices always valid
    // stage nh half (always valid)
    for (int x = tid; x < RPB * K; x += 256) {
        int r = x / K, k = x - r * K;
        long g = (long)r0 * K + x;
        sJW[r][k] = make_int2(nh_idx[g], __float_as_int(nh_e[g]));
    }
    __syncthreads();                   // sCnt init visible before atomics
    // stage int half (masked)
    for (int x = tid; x < RPB * K; x += 256) {
        int r = x / K, k = x - r * K;
        long g = (long)r0 * K + x;
        int   j = int_idx[g];
        float w = int_e[g];
        bool  valid = (j >= 0);
        sJW[r][K + k] = make_int2(valid ? j : 0, valid ? __float_as_int(w) : 0);
        if (valid) atomicAdd(&sCnt[r], 1);
    }
    __syncthreads();

    const int slice = tid >> 6;        // wave id = feature slice
    const int lane  = tid & 63;
    const int q     = lane & 15;
    const int rsub  = lane >> 4;       // row within quad
    const uint* __restrict__ src = vb_u + slice * 16 + q;

    #pragma unroll 1
    for (int rq = 0; rq < RPB / 4; ++rq) {
        const int r = rq * 4 + rsub;
        float ax = 0.f, ay = 0.f;
        #pragma unroll 8
        for (int k = 0; k < 2 * K; ++k) {
            int2  jw = sJW[r][k];
            float w  = __int_as_float(jw.y);
            uint  p  = src[(size_t)jw.x * 128];
            ax = fmaf(w, __uint_as_float(p << 16), ax);
            ay = fmaf(w, __uint_as_float(p & 0xffff0000u), ay);
        }
        float inv = 1.f / (float)sCnt[r];
        vagg_u[(size_t)(r0 + r) * 128 + 64 + slice * 16 + q] =
            (uint)f2bf(ax * inv) | ((uint)f2bf(ay * inv) << 16);
    }
}

// ---------------------------------------------------------------------------
// Fused MFMA GEMM: out = relu(vb[N,256] @ Wcat[256,128] + bv)
// ct loop not unrolled; epilogue inside -> ~8 B-loads + 1 acc live, no spill.
// ---------------------------------------------------------------------------
__global__ __launch_bounds__(256) void gemm_fused(
    const ushort* __restrict__ vb,   // [NV][256] bf16
    const ushort* __restrict__ wt,   // [128][256] bf16
    const float* __restrict__ bv,
    float* __restrict__ out)
{
    const int lane = threadIdx.x & 63;
    const int wave = threadIdx.x >> 6;
    const int r0   = blockIdx.x * 64 + wave * 16;

    int arow = r0 + (lane & 15);
    if (arow >= NV) arow = NV - 1;           // clamp loads; stores guarded

    const bf16x8* abase = reinterpret_cast<const bf16x8*>(
        vb + (size_t)arow * KCAT + (lane >> 4) * 8);
    bf16x8 a[8];
    #pragma unroll
    for (int ks = 0; ks < 8; ++ks)
        a[ks] = __builtin_nontemporal_load(abase + ks * 4);  // read-once rows

    const ushort* wbase = wt + (size_t)(lane & 15) * KCAT + (lane >> 4) * 8;
    const int col0  = lane & 15;
    const int rbase = r0 + (lane >> 4) * 4;

    #pragma unroll 1
    for (int ct = 0; ct < 8; ++ct) {
        const bf16x8* wb = reinterpret_cast<const bf16x8*>(
            wbase + (size_t)ct * 16 * KCAT);
        f32x4 acc = (f32x4){0.f, 0.f, 0.f, 0.f};
        #pragma unroll
        for (int ks = 0; ks < 8; ++ks) {
            bf16x8 b = wb[ks * 4];           // wt hot in L1/L2
            acc = __builtin_amdgcn_mfma_f32_16x16x32_bf16(a[ks], b, acc, 0, 0, 0);
        }
        int c = ct * 16 + col0;
        float bb = bv[c];
        #pragma unroll
        for (int reg = 0; reg < 4; ++reg) {
            int r = rbase + reg;
            if (r < NV) {
                float z = acc[reg] + bb;
                __builtin_nontemporal_store(fmaxf(z, 0.f), out + (size_t)r * F + c);
            }
        }
    }
}

// ---------------------------------------------------------------------------
extern "C" void kernel_launch(void* const* d_in, const int* in_sizes, int n_in,
                              void* d_out, int out_size, void* d_ws, size_t ws_size,
                              hipStream_t stream)
{
    const float* v       = (const float*)d_in[0];
    const int*   nh_idx  = (const int*)  d_in[1];
    const int*   int_idx = (const int*)  d_in[2];
    const float* nh_e    = (const float*)d_in[3];
    const float* int_e   = (const float*)d_in[4];
    const float* Wvc     = (const float*)d_in[5];
    const float* Wvn     = (const float*)d_in[6];
    const float* bv      = (const float*)d_in[7];
    float* out = (float*)d_out;

    ushort* vb = (ushort*)d_ws;                       // NV*256 bf16 = 25.6 MB
    ushort* wt = vb + (size_t)NV * KCAT;              // 128*256 bf16 = 64 KB

    prep_kernel<<<NV * F / 4 / 256 + F * KCAT / 256, 256, 0, stream>>>(
        (const f32x4*)v, vb, Wvc, Wvn, wt);
    agg_lds<<<NV / RPB, 256, 0, stream>>>((const uint*)vb, nh_idx, int_idx,
                                          nh_e, int_e, (uint*)vb);
    gemm_fused<<<(NV + 63) / 64, 256, 0, stream>>>(vb, wt, bv, out);
}

// Round 10
// 160.039 us; speedup vs baseline: 1.3816x; 1.1207x over previous
//
#include <hip/hip_runtime.h>

#define NV 50000
#define F 128
#define K 20
#define KCAT 256   // concatenated inner dim: [V | vagg]
#define RPB 16     // rows per block in agg

typedef __attribute__((ext_vector_type(8))) __bf16 bf16x8;
typedef __attribute__((ext_vector_type(4))) float f32x4;
typedef __attribute__((ext_vector_type(2))) float f32x2;

__device__ inline ushort f2bf(float x) {     // RNE f32 -> bf16
    uint u = __float_as_uint(x);
    return (ushort)((u + 0x7fffu + ((u >> 16) & 1u)) >> 16);
}

// ws layout: vb=[NV][256] bf16 (cols 0..127 = bf16(V), 128..255 = bf16(vagg))
//            wt=[128][256] bf16, wt[c][k] = bf16(Wcat[k][c])
//            v8=[NV][128] fp8-e4m3 copy of V (gather source, 6.4 MB)

// ---------------------------------------------------------------------------
// prep: blocks 0..6249 convert V fp32 -> bf16 (vb) AND fp8-e4m3 (v8);
// remaining 128 blocks build the transposed bf16 weight matrix.
// ---------------------------------------------------------------------------
__global__ __launch_bounds__(256) void prep_kernel(
    const f32x4* __restrict__ v4, ushort* __restrict__ vb,
    uchar* __restrict__ v8,
    const float* __restrict__ Wvc, const float* __restrict__ Wvn,
    ushort* __restrict__ wt)
{
    int bid = blockIdx.x;
    if (bid < NV * F / 4 / 256) {          // 6250 blocks
        int t = bid * 256 + threadIdx.x;
        int e = t * 4;
        int row = e >> 7, f = e & 127;
        f32x4 x = __builtin_nontemporal_load(v4 + t);   // pure stream
        uint2 o;
        o.x = (uint)f2bf(x[0]) | ((uint)f2bf(x[1]) << 16);
        o.y = (uint)f2bf(x[2]) | ((uint)f2bf(x[3]) << 16);
        *reinterpret_cast<uint2*>(vb + (size_t)row * KCAT + f) = o;
        int p8 = __builtin_amdgcn_cvt_pk_fp8_f32(x[0], x[1], 0, false);
        p8     = __builtin_amdgcn_cvt_pk_fp8_f32(x[2], x[3], p8, true);
        *reinterpret_cast<uint*>(v8 + (size_t)row * F + f) = (uint)p8;
    } else {
        int t = (bid - NV * F / 4 / 256) * 256 + threadIdx.x;  // < 32768
        int c = t >> 8, k = t & 255;
        float w = (k < F) ? Wvc[k * F + c] : Wvn[(k - F) * F + c];
        wt[t] = f2bf(w);
    }
}

// ---------------------------------------------------------------------------
// agg (fp8 gather): block = 16 rows. idx/edge/validity staged once in LDS
// (sJW padded to 41 int2/row: breaks the 320B-stride 2-way bank conflict).
// Wave w owns feature-slice w (32 feats = 32 B fp8). Within a wave:
// 4 lanes/row (uint2 = 8 fp8 each), 16 rows in flight -> 40 gathers/lane
// total, 8B each. Slice working set = 1.6 MB -> L2-resident per XCD under
// bid%8 round-robin. Unpack via v_cvt_pk_f32_fp8 (2 f32/inst).
// Output written as bf16 into vb cols 128..255 (16 B/lane store).
// ---------------------------------------------------------------------------
__global__ __launch_bounds__(256) void agg_fp8(
    const uchar* __restrict__ v8,    // [NV][128] fp8
    const int* __restrict__ nh_idx, const int* __restrict__ int_idx,
    const float* __restrict__ nh_e, const float* __restrict__ int_e,
    ushort* __restrict__ vb)         // [NV][256] bf16; writes cols 128..255
{
    __shared__ int2 sJW[RPB][2 * K + 1];   // {index, weight-bits}; +1 pad
    __shared__ int  sCnt[RPB];

    const int tid = threadIdx.x;
    const int r0  = blockIdx.x * RPB;

    if (tid < RPB) sCnt[tid] = K;      // nh indices always valid
    for (int x = tid; x < RPB * K; x += 256) {
        int r = x / K, k = x - r * K;
        long g = (long)r0 * K + x;
        sJW[r][k] = make_int2(nh_idx[g], __float_as_int(nh_e[g]));
    }
    __syncthreads();                   // sCnt init visible before atomics
    for (int x = tid; x < RPB * K; x += 256) {
        int r = x / K, k = x - r * K;
        long g = (long)r0 * K + x;
        int   j = int_idx[g];
        float w = int_e[g];
        bool  valid = (j >= 0);
        sJW[r][K + k] = make_int2(valid ? j : 0, valid ? __float_as_int(w) : 0);
        if (valid) atomicAdd(&sCnt[r], 1);
    }
    __syncthreads();

    const int slice = tid >> 6;        // wave id = feature slice (32 feats)
    const int lane  = tid & 63;
    const int q     = lane & 3;        // 8-byte chunk within the 32 B slice
    const int r     = lane >> 2;       // row 0..15
    const uchar* __restrict__ src = v8 + slice * 32 + q * 8;

    float acc[8];
    #pragma unroll
    for (int i = 0; i < 8; ++i) acc[i] = 0.f;

    #pragma unroll 4
    for (int k = 0; k < 2 * K; ++k) {
        int2  jw = sJW[r][k];
        float w  = __int_as_float(jw.y);
        uint2 p  = *reinterpret_cast<const uint2*>(src + (size_t)jw.x * F);
        f32x2 f01 = __builtin_amdgcn_cvt_pk_f32_fp8(p.x, false);
        f32x2 f23 = __builtin_amdgcn_cvt_pk_f32_fp8(p.x, true);
        f32x2 f45 = __builtin_amdgcn_cvt_pk_f32_fp8(p.y, false);
        f32x2 f67 = __builtin_amdgcn_cvt_pk_f32_fp8(p.y, true);
        acc[0] = fmaf(w, f01[0], acc[0]);
        acc[1] = fmaf(w, f01[1], acc[1]);
        acc[2] = fmaf(w, f23[0], acc[2]);
        acc[3] = fmaf(w, f23[1], acc[3]);
        acc[4] = fmaf(w, f45[0], acc[4]);
        acc[5] = fmaf(w, f45[1], acc[5]);
        acc[6] = fmaf(w, f67[0], acc[6]);
        acc[7] = fmaf(w, f67[1], acc[7]);
    }
    float inv = 1.f / (float)sCnt[r];
    uint4 o;
    o.x = (uint)f2bf(acc[0] * inv) | ((uint)f2bf(acc[1] * inv) << 16);
    o.y = (uint)f2bf(acc[2] * inv) | ((uint)f2bf(acc[3] * inv) << 16);
    o.z = (uint)f2bf(acc[4] * inv) | ((uint)f2bf(acc[5] * inv) << 16);
    o.w = (uint)f2bf(acc[6] * inv) | ((uint)f2bf(acc[7] * inv) << 16);
    *reinterpret_cast<uint4*>(vb + (size_t)(r0 + r) * KCAT + F + slice * 32 + q * 8) = o;
}

// ---------------------------------------------------------------------------
// Fused MFMA GEMM: out = relu(vb[N,256] @ Wcat[256,128] + bv)
// ct loop not unrolled; epilogue inside -> ~8 B-loads + 1 acc live, no spill.
// ---------------------------------------------------------------------------
__global__ __launch_bounds__(256) void gemm_fused(
    const ushort* __restrict__ vb,   // [NV][256] bf16
    const ushort* __restrict__ wt,   // [128][256] bf16
    const float* __restrict__ bv,
    float* __restrict__ out)
{
    const int lane = threadIdx.x & 63;
    const int wave = threadIdx.x >> 6;
    const int r0   = blockIdx.x * 64 + wave * 16;

    int arow = r0 + (lane & 15);
    if (arow >= NV) arow = NV - 1;           // clamp loads; stores guarded

    const bf16x8* abase = reinterpret_cast<const bf16x8*>(
        vb + (size_t)arow * KCAT + (lane >> 4) * 8);
    bf16x8 a[8];
    #pragma unroll
    for (int ks = 0; ks < 8; ++ks)
        a[ks] = __builtin_nontemporal_load(abase + ks * 4);  // read-once rows

    const ushort* wbase = wt + (size_t)(lane & 15) * KCAT + (lane >> 4) * 8;
    const int col0  = lane & 15;
    const int rbase = r0 + (lane >> 4) * 4;

    #pragma unroll 1
    for (int ct = 0; ct < 8; ++ct) {
        const bf16x8* wb = reinterpret_cast<const bf16x8*>(
            wbase + (size_t)ct * 16 * KCAT);
        f32x4 acc = (f32x4){0.f, 0.f, 0.f, 0.f};
        #pragma unroll
        for (int ks = 0; ks < 8; ++ks) {
            bf16x8 b = wb[ks * 4];           // wt hot in L1/L2
            acc = __builtin_amdgcn_mfma_f32_16x16x32_bf16(a[ks], b, acc, 0, 0, 0);
        }
        int c = ct * 16 + col0;
        float bb = bv[c];
        #pragma unroll
        for (int reg = 0; reg < 4; ++reg) {
            int r = rbase + reg;
            if (r < NV) {
                float z = acc[reg] + bb;
                __builtin_nontemporal_store(fmaxf(z, 0.f), out + (size_t)r * F + c);
            }
        }
    }
}

// ---------------------------------------------------------------------------
extern "C" void kernel_launch(void* const* d_in, const int* in_sizes, int n_in,
                              void* d_out, int out_size, void* d_ws, size_t ws_size,
                              hipStream_t stream)
{
    const float* v       = (const float*)d_in[0];
    const int*   nh_idx  = (const int*)  d_in[1];
    const int*   int_idx = (const int*)  d_in[2];
    const float* nh_e    = (const float*)d_in[3];
    const float* int_e   = (const float*)d_in[4];
    const float* Wvc     = (const float*)d_in[5];
    const float* Wvn     = (const float*)d_in[6];
    const float* bv      = (const float*)d_in[7];
    float* out = (float*)d_out;

    ushort* vb = (ushort*)d_ws;                       // NV*256 bf16 = 25.6 MB
    ushort* wt = vb + (size_t)NV * KCAT;              // 128*256 bf16 = 64 KB
    uchar*  v8 = (uchar*)(wt + (size_t)F * KCAT);     // NV*128 fp8 = 6.4 MB

    prep_kernel<<<NV * F / 4 / 256 + F * KCAT / 256, 256, 0, stream>>>(
        (const f32x4*)v, vb, v8, Wvc, Wvn, wt);
    agg_fp8<<<NV / RPB, 256, 0, stream>>>(v8, nh_idx, int_idx, nh_e, int_e, vb);
    gemm_fused<<<(NV + 63) / 64, 256, 0, stream>>>(vb, wt, bv, out);
}

// Round 12
// 156.180 us; speedup vs baseline: 1.4157x; 1.0247x over previous
//
#include <hip/hip_runtime.h>

#define NV 50000
#define F 128
#define K 20
#define KCAT 256   // concatenated inner dim: [V | vagg]
#define RPB 32     // rows per block in agg

typedef __attribute__((ext_vector_type(8))) __bf16 bf16x8;
typedef __attribute__((ext_vector_type(4))) float f32x4;
typedef __attribute__((ext_vector_type(2))) float f32x2;

__device__ inline ushort f2bf(float x) {     // RNE f32 -> bf16
    uint u = __float_as_uint(x);
    return (ushort)((u + 0x7fffu + ((u >> 16) & 1u)) >> 16);
}

// ws layout: vb=[NV][256] bf16 (cols 0..127 = bf16(V), 128..255 = bf16(vagg))
//            wt=[128][256] bf16, wt[c][k] = bf16(Wcat[k][c])
//            v8=[NV][128] fp8-e4m3 copy of V (gather source, 6.4 MB)

// ---------------------------------------------------------------------------
// prep: blocks 0..6249 convert V fp32 -> bf16 (vb) AND fp8-e4m3 (v8);
// remaining 128 blocks build the transposed bf16 weight matrix.
// ---------------------------------------------------------------------------
__global__ __launch_bounds__(256) void prep_kernel(
    const f32x4* __restrict__ v4, ushort* __restrict__ vb,
    uchar* __restrict__ v8,
    const float* __restrict__ Wvc, const float* __restrict__ Wvn,
    ushort* __restrict__ wt)
{
    int bid = blockIdx.x;
    if (bid < NV * F / 4 / 256) {          // 6250 blocks
        int t = bid * 256 + threadIdx.x;
        int e = t * 4;
        int row = e >> 7, f = e & 127;
        f32x4 x = __builtin_nontemporal_load(v4 + t);   // pure stream
        uint2 o;
        o.x = (uint)f2bf(x[0]) | ((uint)f2bf(x[1]) << 16);
        o.y = (uint)f2bf(x[2]) | ((uint)f2bf(x[3]) << 16);
        *reinterpret_cast<uint2*>(vb + (size_t)row * KCAT + f) = o;
        int p8 = __builtin_amdgcn_cvt_pk_fp8_f32(x[0], x[1], 0, false);
        p8     = __builtin_amdgcn_cvt_pk_fp8_f32(x[2], x[3], p8, true);
        *reinterpret_cast<uint*>(v8 + (size_t)row * F + f) = (uint)p8;
    } else {
        int t = (bid - NV * F / 4 / 256) * 256 + threadIdx.x;  // < 32768
        int c = t >> 8, k = t & 255;
        float w = (k < F) ? Wvc[k * F + c] : Wvn[(k - F) * F + c];
        wt[t] = f2bf(w);
    }
}

// ---------------------------------------------------------------------------
// agg (full-line fp8 gather): block = 32 rows, 4 waves. idx/edge/validity
// staged once in LDS (padded rows). Gather granularity = FULL row: 8 lanes x
// uint4 (16 fp8) = 128 B = exactly one cacheline per row-request (was 4x
// 32 B partial-line requests). Wave covers 8 rows/iter; each lane owns 16
// features of one row; 40 serial k-iters with unroll-4 for MLP.
// Output: 16 bf16 (32 B, two uint4 stores) into vb cols 128..255.
// ---------------------------------------------------------------------------
__global__ __launch_bounds__(256) void agg_fp8(
    const uchar* __restrict__ v8,    // [NV][128] fp8
    const int* __restrict__ nh_idx, const int* __restrict__ int_idx,
    const float* __restrict__ nh_e, const float* __restrict__ int_e,
    ushort* __restrict__ vb)         // [NV][256] bf16; writes cols 128..255
{
    __shared__ int2 sJW[RPB][2 * K + 1];   // {index, weight-bits}; +1 pad
    __shared__ int  sCnt[RPB];

    const int tid = threadIdx.x;
    const int r0  = blockIdx.x * RPB;

    if (tid < RPB) sCnt[tid] = K;      // nh indices always valid
    for (int x = tid; x < RPB * K; x += 256) {
        int r = x / K, k = x - r * K;
        int row = r0 + r;
        int2 jw = make_int2(0, 0);
        if (row < NV) {
            long g = (long)row * K + k;
            jw = make_int2(nh_idx[g], __float_as_int(nh_e[g]));
        }
        sJW[r][k] = jw;
    }
    __syncthreads();                   // sCnt init visible before atomics
    for (int x = tid; x < RPB * K; x += 256) {
        int r = x / K, k = x - r * K;
        int row = r0 + r;
        int2 jw = make_int2(0, 0);
        bool valid = false;
        if (row < NV) {
            long g = (long)row * K + k;
            int   j = int_idx[g];
            float w = int_e[g];
            valid = (j >= 0);
            jw = make_int2(valid ? j : 0, valid ? __float_as_int(w) : 0);
        }
        sJW[r][K + k] = jw;
        if (valid) atomicAdd(&sCnt[r], 1);
    }
    __syncthreads();

    const int lane  = tid & 63;
    const int wave  = tid >> 6;
    const int chunk = lane & 7;              // 16-byte chunk = feats 16c..16c+15
    const int rw    = (wave << 3) + (lane >> 3);   // row in block, 0..31
    const uchar* __restrict__ src = v8 + chunk * 16;

    float acc[16];
    #pragma unroll
    for (int i = 0; i < 16; ++i) acc[i] = 0.f;

    #pragma unroll 4
    for (int k = 0; k < 2 * K; ++k) {
        int2  jw = sJW[rw][k];               // broadcast across the 8 lanes
        float w  = __int_as_float(jw.y);
        uint4 p  = *reinterpret_cast<const uint4*>(src + (size_t)jw.x * F);
        f32x2 f0 = __builtin_amdgcn_cvt_pk_f32_fp8(p.x, false);
        f32x2 f1 = __builtin_amdgcn_cvt_pk_f32_fp8(p.x, true);
        f32x2 f2 = __builtin_amdgcn_cvt_pk_f32_fp8(p.y, false);
        f32x2 f3 = __builtin_amdgcn_cvt_pk_f32_fp8(p.y, true);
        f32x2 f4 = __builtin_amdgcn_cvt_pk_f32_fp8(p.z, false);
        f32x2 f5 = __builtin_amdgcn_cvt_pk_f32_fp8(p.z, true);
        f32x2 f6 = __builtin_amdgcn_cvt_pk_f32_fp8(p.w, false);
        f32x2 f7 = __builtin_amdgcn_cvt_pk_f32_fp8(p.w, true);
        acc[0]  = fmaf(w, f0[0], acc[0]);   acc[1]  = fmaf(w, f0[1], acc[1]);
        acc[2]  = fmaf(w, f1[0], acc[2]);   acc[3]  = fmaf(w, f1[1], acc[3]);
        acc[4]  = fmaf(w, f2[0], acc[4]);   acc[5]  = fmaf(w, f2[1], acc[5]);
        acc[6]  = fmaf(w, f3[0], acc[6]);   acc[7]  = fmaf(w, f3[1], acc[7]);
        acc[8]  = fmaf(w, f4[0], acc[8]);   acc[9]  = fmaf(w, f4[1], acc[9]);
        acc[10] = fmaf(w, f5[0], acc[10]);  acc[11] = fmaf(w, f5[1], acc[11]);
        acc[12] = fmaf(w, f6[0], acc[12]);  acc[13] = fmaf(w, f6[1], acc[13]);
        acc[14] = fmaf(w, f7[0], acc[14]);  acc[15] = fmaf(w, f7[1], acc[15]);
    }

    const int row = r0 + rw;
    if (row < NV) {
        float inv = 1.f / (float)sCnt[rw];
        uint4 o0, o1;
        o0.x = (uint)f2bf(acc[0]  * inv) | ((uint)f2bf(acc[1]  * inv) << 16);
        o0.y = (uint)f2bf(acc[2]  * inv) | ((uint)f2bf(acc[3]  * inv) << 16);
        o0.z = (uint)f2bf(acc[4]  * inv) | ((uint)f2bf(acc[5]  * inv) << 16);
        o0.w = (uint)f2bf(acc[6]  * inv) | ((uint)f2bf(acc[7]  * inv) << 16);
        o1.x = (uint)f2bf(acc[8]  * inv) | ((uint)f2bf(acc[9]  * inv) << 16);
        o1.y = (uint)f2bf(acc[10] * inv) | ((uint)f2bf(acc[11] * inv) << 16);
        o1.z = (uint)f2bf(acc[12] * inv) | ((uint)f2bf(acc[13] * inv) << 16);
        o1.w = (uint)f2bf(acc[14] * inv) | ((uint)f2bf(acc[15] * inv) << 16);
        uint4* dst = reinterpret_cast<uint4*>(vb + (size_t)row * KCAT + F + chunk * 16);
        dst[0] = o0;
        dst[1] = o1;
    }
}

// ---------------------------------------------------------------------------
// Fused MFMA GEMM: out = relu(vb[N,256] @ Wcat[256,128] + bv)
// ct loop not unrolled; epilogue inside -> ~8 B-loads + 1 acc live, no spill.
// ---------------------------------------------------------------------------
__global__ __launch_bounds__(256) void gemm_fused(
    const ushort* __restrict__ vb,   // [NV][256] bf16
    const ushort* __restrict__ wt,   // [128][256] bf16
    const float* __restrict__ bv,
    float* __restrict__ out)
{
    const int lane = threadIdx.x & 63;
    const int wave = threadIdx.x >> 6;
    const int r0   = blockIdx.x * 64 + wave * 16;

    int arow = r0 + (lane & 15);
    if (arow >= NV) arow = NV - 1;           // clamp loads; stores guarded

    const bf16x8* abase = reinterpret_cast<const bf16x8*>(
        vb + (size_t)arow * KCAT + (lane >> 4) * 8);
    bf16x8 a[8];
    #pragma unroll
    for (int ks = 0; ks < 8; ++ks)
        a[ks] = __builtin_nontemporal_load(abase + ks * 4);  // read-once rows

    const ushort* wbase = wt + (size_t)(lane & 15) * KCAT + (lane >> 4) * 8;
    const int col0  = lane & 15;
    const int rbase = r0 + (lane >> 4) * 4;

    #pragma unroll 1
    for (int ct = 0; ct < 8; ++ct) {
        const bf16x8* wb = reinterpret_cast<const bf16x8*>(
            wbase + (size_t)ct * 16 * KCAT);
        f32x4 acc = (f32x4){0.f, 0.f, 0.f, 0.f};
        #pragma unroll
        for (int ks = 0; ks < 8; ++ks) {
            bf16x8 b = wb[ks * 4];           // wt hot in L1/L2
            acc = __builtin_amdgcn_mfma_f32_16x16x32_bf16(a[ks], b, acc, 0, 0, 0);
        }
        int c = ct * 16 + col0;
        float bb = bv[c];
        #pragma unroll
        for (int reg = 0; reg < 4; ++reg) {
            int r = rbase + reg;
            if (r < NV) {
                float z = acc[reg] + bb;
                __builtin_nontemporal_store(fmaxf(z, 0.f), out + (size_t)r * F + c);
            }
        }
    }
}

// ---------------------------------------------------------------------------
extern "C" void kernel_launch(void* const* d_in, const int* in_sizes, int n_in,
                              void* d_out, int out_size, void* d_ws, size_t ws_size,
                              hipStream_t stream)
{
    const float* v       = (const float*)d_in[0];
    const int*   nh_idx  = (const int*)  d_in[1];
    const int*   int_idx = (const int*)  d_in[2];
    const float* nh_e    = (const float*)d_in[3];
    const float* int_e   = (const float*)d_in[4];
    const float* Wvc     = (const float*)d_in[5];
    const float* Wvn     = (const float*)d_in[6];
    const float* bv      = (const float*)d_in[7];
    float* out = (float*)d_out;

    ushort* vb = (ushort*)d_ws;                       // NV*256 bf16 = 25.6 MB
    ushort* wt = vb + (size_t)NV * KCAT;              // 128*256 bf16 = 64 KB
    uchar*  v8 = (uchar*)(wt + (size_t)F * KCAT);     // NV*128 fp8 = 6.4 MB

    prep_kernel<<<NV * F / 4 / 256 + F * KCAT / 256, 256, 0, stream>>>(
        (const f32x4*)v, vb, v8, Wvc, Wvn, wt);
    agg_fp8<<<(NV + RPB - 1) / RPB, 256, 0, stream>>>(v8, nh_idx, int_idx,
                                                      nh_e, int_e, vb);
    gemm_fused<<<(NV + 63) / 64, 256, 0, stream>>>(vb, wt, bv, out);
}

// Round 16
// 152.126 us; speedup vs baseline: 1.4535x; 1.0266x over previous
//
#include <hip/hip_runtime.h>

#define NV 50000
#define F 128
#define K 20
#define KCAT 256   // concatenated inner dim: [V | vagg]
#define RPB 64     // rows per block in fused kernel
#define LDSW (F + 8)   // padded LDS row width (bf16) -> 272 B stride

typedef __attribute__((ext_vector_type(8))) __bf16 bf16x8;
typedef __attribute__((ext_vector_type(4))) float f32x4;
typedef __attribute__((ext_vector_type(2))) float f32x2;

__device__ inline ushort f2bf(float x) {     // RNE f32 -> bf16
    uint u = __float_as_uint(x);
    return (ushort)((u + 0x7fffu + ((u >> 16) & 1u)) >> 16);
}

// ws layout: v8=[NV][128] fp8-e4m3 copy of V (gather source, 6.4 MB)
//            wt=[128][256] bf16, wt[c][k] = bf16(Wcat[k][c])

// ---------------------------------------------------------------------------
// prep: blocks 0..6249 convert V fp32 -> fp8-e4m3 (v8); remaining 128 blocks
// build the transposed bf16 weight matrix. (No more bf16 vb: the fused kernel
// converts V fp32 -> bf16 fragments in-register.)
// ---------------------------------------------------------------------------
__global__ __launch_bounds__(256) void prep_kernel(
    const f32x4* __restrict__ v4, uchar* __restrict__ v8,
    const float* __restrict__ Wvc, const float* __restrict__ Wvn,
    ushort* __restrict__ wt)
{
    int bid = blockIdx.x;
    if (bid < NV * F / 4 / 256) {          // 6250 blocks
        int t = bid * 256 + threadIdx.x;
        int e = t * 4;
        int row = e >> 7, f = e & 127;
        f32x4 x = __builtin_nontemporal_load(v4 + t);   // pure stream
        int p8 = __builtin_amdgcn_cvt_pk_fp8_f32(x[0], x[1], 0, false);
        p8     = __builtin_amdgcn_cvt_pk_fp8_f32(x[2], x[3], p8, true);
        *reinterpret_cast<uint*>(v8 + (size_t)row * F + f) = (uint)p8;
    } else {
        int t = (bid - NV * F / 4 / 256) * 256 + threadIdx.x;  // < 32768
        int c = t >> 8, k = t & 255;
        float w = (k < F) ? Wvc[k * F + c] : Wvn[(k - F) * F + c];
        wt[t] = f2bf(w);
    }
}

// ---------------------------------------------------------------------------
// fused agg + GEMM: block = 64 rows, 4 waves.
// Phase 1 (agg): idx/edge/validity staged once in LDS; full-cacheline fp8
// gathers (8 lanes x uint4 = 128 B/row); vagg written as bf16 to padded LDS
// (stride 272 B -> ~2-way bank aliasing, free). 2 passes of 32 rows.
// Phase 2 (gemm): out = relu([V | vagg] @ Wcat + bv). Wave w owns rows
// w*16..w*16+15. A-frags ks=0..3 from fp32 V (convert in-register, same f2bf
// rounding as before); ks=4..7 from LDS vagg. B-frags from wt (L2-hot).
// ---------------------------------------------------------------------------
__global__ __launch_bounds__(256) void fused_kernel(
    const float* __restrict__ v,     // [NV][128] fp32
    const uchar* __restrict__ v8,    // [NV][128] fp8
    const int* __restrict__ nh_idx, const int* __restrict__ int_idx,
    const float* __restrict__ nh_e, const float* __restrict__ int_e,
    const ushort* __restrict__ wt,   // [128][256] bf16
    const float* __restrict__ bv,
    float* __restrict__ out)
{
    __shared__ int2   sJW[RPB][2 * K + 1];   // {index, weight-bits}; +1 pad
    __shared__ int    sCnt[RPB];
    __shared__ ushort sVA[RPB][LDSW];        // vagg bf16, padded

    const int tid = threadIdx.x;
    const int r0  = blockIdx.x * RPB;

    if (tid < RPB) sCnt[tid] = K;      // nh indices always valid
    for (int x = tid; x < RPB * K; x += 256) {
        int r = x / K, k = x - r * K;
        int row = r0 + r;
        int2 jw = make_int2(0, 0);
        if (row < NV) {
            long g = (long)row * K + k;
            jw = make_int2(nh_idx[g], __float_as_int(nh_e[g]));
        }
        sJW[r][k] = jw;
    }
    __syncthreads();                   // sCnt init visible before atomics
    for (int x = tid; x < RPB * K; x += 256) {
        int r = x / K, k = x - r * K;
        int row = r0 + r;
        int2 jw = make_int2(0, 0);
        bool valid = false;
        if (row < NV) {
            long g = (long)row * K + k;
            int   j = int_idx[g];
            float w = int_e[g];
            valid = (j >= 0);
            jw = make_int2(valid ? j : 0, valid ? __float_as_int(w) : 0);
        }
        sJW[r][K + k] = jw;
        if (valid) atomicAdd(&sCnt[r], 1);
    }
    __syncthreads();

    const int lane  = tid & 63;
    const int wave  = tid >> 6;
    const int chunk = lane & 7;              // 16-byte chunk = feats 16c..16c+15
    const uchar* __restrict__ gsrc = v8 + chunk * 16;

    // ---- Phase 1: aggregate 64 rows in 2 passes of 32 ----
    #pragma unroll 1
    for (int pass = 0; pass < 2; ++pass) {
        const int rw = pass * 32 + (wave << 3) + (lane >> 3);   // row in block
        float acc[16];
        #pragma unroll
        for (int i = 0; i < 16; ++i) acc[i] = 0.f;

        #pragma unroll 4
        for (int k = 0; k < 2 * K; ++k) {
            int2  jw = sJW[rw][k];
            float w  = __int_as_float(jw.y);
            uint4 p  = *reinterpret_cast<const uint4*>(gsrc + (size_t)jw.x * F);
            f32x2 f0 = __builtin_amdgcn_cvt_pk_f32_fp8(p.x, false);
            f32x2 f1 = __builtin_amdgcn_cvt_pk_f32_fp8(p.x, true);
            f32x2 f2 = __builtin_amdgcn_cvt_pk_f32_fp8(p.y, false);
            f32x2 f3 = __builtin_amdgcn_cvt_pk_f32_fp8(p.y, true);
            f32x2 f4 = __builtin_amdgcn_cvt_pk_f32_fp8(p.z, false);
            f32x2 f5 = __builtin_amdgcn_cvt_pk_f32_fp8(p.z, true);
            f32x2 f6 = __builtin_amdgcn_cvt_pk_f32_fp8(p.w, false);
            f32x2 f7 = __builtin_amdgcn_cvt_pk_f32_fp8(p.w, true);
            acc[0]  = fmaf(w, f0[0], acc[0]);   acc[1]  = fmaf(w, f0[1], acc[1]);
            acc[2]  = fmaf(w, f1[0], acc[2]);   acc[3]  = fmaf(w, f1[1], acc[3]);
            acc[4]  = fmaf(w, f2[0], acc[4]);   acc[5]  = fmaf(w, f2[1], acc[5]);
            acc[6]  = fmaf(w, f3[0], acc[6]);   acc[7]  = fmaf(w, f3[1], acc[7]);
            acc[8]  = fmaf(w, f4[0], acc[8]);   acc[9]  = fmaf(w, f4[1], acc[9]);
            acc[10] = fmaf(w, f5[0], acc[10]);  acc[11] = fmaf(w, f5[1], acc[11]);
            acc[12] = fmaf(w, f6[0], acc[12]);  acc[13] = fmaf(w, f6[1], acc[13]);
            acc[14] = fmaf(w, f7[0], acc[14]);  acc[15] = fmaf(w, f7[1], acc[15]);
        }
        float inv = 1.f / (float)sCnt[rw];
        uint4 o0, o1;
        o0.x = (uint)f2bf(acc[0]  * inv) | ((uint)f2bf(acc[1]  * inv) << 16);
        o0.y = (uint)f2bf(acc[2]  * inv) | ((uint)f2bf(acc[3]  * inv) << 16);
        o0.z = (uint)f2bf(acc[4]  * inv) | ((uint)f2bf(acc[5]  * inv) << 16);
        o0.w = (uint)f2bf(acc[6]  * inv) | ((uint)f2bf(acc[7]  * inv) << 16);
        o1.x = (uint)f2bf(acc[8]  * inv) | ((uint)f2bf(acc[9]  * inv) << 16);
        o1.y = (uint)f2bf(acc[10] * inv) | ((uint)f2bf(acc[11] * inv) << 16);
        o1.z = (uint)f2bf(acc[12] * inv) | ((uint)f2bf(acc[13] * inv) << 16);
        o1.w = (uint)f2bf(acc[14] * inv) | ((uint)f2bf(acc[15] * inv) << 16);
        uint4* dst = reinterpret_cast<uint4*>(&sVA[rw][chunk * 16]);
        dst[0] = o0;
        dst[1] = o1;
    }
    __syncthreads();

    // ---- Phase 2: MFMA GEMM for this block's 64 rows ----
    const int rloc = wave * 16 + (lane & 15);     // row within block
    int arow = r0 + rloc;
    if (arow >= NV) arow = NV - 1;                // clamp loads; stores guarded
    const int g = lane >> 4;                      // k-subgroup 0..3

    bf16x8 a[8];
    // ks=0..3: from fp32 V, convert in-register (same rounding as f2bf path)
    #pragma unroll
    for (int kk = 0; kk < 4; ++kk) {
        const float* vp = v + (size_t)arow * F + g * 8 + kk * 32;
        f32x4 x0 = *reinterpret_cast<const f32x4*>(vp);
        f32x4 x1 = *reinterpret_cast<const f32x4*>(vp + 4);
        union { bf16x8 vv; ushort s[8]; } af;
        af.s[0] = f2bf(x0[0]); af.s[1] = f2bf(x0[1]);
        af.s[2] = f2bf(x0[2]); af.s[3] = f2bf(x0[3]);
        af.s[4] = f2bf(x1[0]); af.s[5] = f2bf(x1[1]);
        af.s[6] = f2bf(x1[2]); af.s[7] = f2bf(x1[3]);
        a[kk] = af.vv;
    }
    // ks=4..7: vagg from LDS
    #pragma unroll
    for (int kk = 0; kk < 4; ++kk)
        a[4 + kk] = *reinterpret_cast<const bf16x8*>(&sVA[rloc][g * 8 + kk * 32]);

    const ushort* wbase = wt + (size_t)(lane & 15) * KCAT + g * 8;
    const int col0  = lane & 15;
    const int rbase = r0 + wave * 16 + g * 4;

    #pragma unroll 1
    for (int ct = 0; ct < 8; ++ct) {
        const bf16x8* wb = reinterpret_cast<const bf16x8*>(
            wbase + (size_t)ct * 16 * KCAT);
        f32x4 acc = (f32x4){0.f, 0.f, 0.f, 0.f};
        #pragma unroll
        for (int ks = 0; ks < 8; ++ks) {
            bf16x8 b = wb[ks * 4];           // wt hot in L1/L2
            acc = __builtin_amdgcn_mfma_f32_16x16x32_bf16(a[ks], b, acc, 0, 0, 0);
        }
        int c = ct * 16 + col0;
        float bb = bv[c];
        #pragma unroll
        for (int reg = 0; reg < 4; ++reg) {
            int r = rbase + reg;
            if (r < NV) {
                float z = acc[reg] + bb;
                __builtin_nontemporal_store(fmaxf(z, 0.f), out + (size_t)r * F + c);
            }
        }
    }
}

// ---------------------------------------------------------------------------
extern "C" void kernel_launch(void* const* d_in, const int* in_sizes, int n_in,
                              void* d_out, int out_size, void* d_ws, size_t ws_size,
                              hipStream_t stream)
{
    const float* v       = (const float*)d_in[0];
    const int*   nh_idx  = (const int*)  d_in[1];
    const int*   int_idx = (const int*)  d_in[2];
    const float* nh_e    = (const float*)d_in[3];
    const float* int_e   = (const float*)d_in[4];
    const float* Wvc     = (const float*)d_in[5];
    const float* Wvn     = (const float*)d_in[6];
    const float* bv      = (const float*)d_in[7];
    float* out = (float*)d_out;

    uchar*  v8 = (uchar*)d_ws;                        // NV*128 fp8 = 6.4 MB
    ushort* wt = (ushort*)(v8 + (size_t)NV * F);      // 128*256 bf16 = 64 KB

    prep_kernel<<<NV * F / 4 / 256 + F * KCAT / 256, 256, 0, stream>>>(
        (const f32x4*)v, v8, Wvc, Wvn, wt);
    fused_kernel<<<(NV + RPB - 1) / RPB, 256, 0, stream>>>(
        v, v8, nh_idx, int_idx, nh_e, int_e, wt, bv, out);
}